// Round 3
// baseline (249.333 us; speedup 1.0000x reference)
//
#include <hip/hip_runtime.h>
#include <cstdint>
#include <math.h>

// GeometricAttention: B=4,H=8,N=2048, D = 8*16 (mv, IPF signs on q) + 16 (s) = 144
// R6: V taken OFF the LDS pipe. V^T repacked fragment-ordered [tile][ks*2+hi][d][8]
// so PV operands are coalesced global_load_dwordx4 direct to VGPRs (L1/L2-served,
// all 8 waves read identical 18KB tile). LDS now stages K only (39KB, dbuf).
// Per-CU LDS traffic/iter: 346KB -> 163KB. V-pack store side now 16B vectorized.

#define BH    32
#define N_    2048
#define DMV   128
#define DS    16
#define D_    144
#define BM    256          // Q rows per block (8 waves x 32 rows)
#define BN    64           // KV rows per iteration
#define NKIT  (N_ / BN)    // 32
#define KSTR  152          // packed K row stride (bf16): 144 data + 8 pad
#define KCHUNKS (BN * KSTR / 8)   // 1216 16B chunks
#define KP_BYTES ((size_t)BH * N_ * KSTR * 2)   // 19,922,944
#define VT_CHUNKS 1152     // per tile: 8 groups (ks*2+hi) x 144 d, 16B each
#define QSCALE 0.12022458674074693f  // (1/12) * log2(e)
#define KPACK_BLOCKS (BH * N_ * 19 / 256)       // 4864
#define TSTR  156          // V-pack LDS transpose stride

typedef __bf16 bf16_8 __attribute__((ext_vector_type(8)));
typedef __bf16 bf16_4 __attribute__((ext_vector_type(4)));
typedef float  f32x4  __attribute__((ext_vector_type(4)));
typedef float  f32x16 __attribute__((ext_vector_type(16)));

#define GLOAD_LDS16(g, l)                                                     \
  __builtin_amdgcn_global_load_lds(                                           \
      (const __attribute__((address_space(1))) void*)(g),                     \
      (__attribute__((address_space(3))) void*)(l), 16, 0, 0)

__device__ __forceinline__ f32x16 mfma32(bf16_8 a, bf16_8 b, f32x16 c) {
  return __builtin_amdgcn_mfma_f32_32x32x16_bf16(a, b, c, 0, 0, 0);
}

__device__ __forceinline__ bf16_4 cvt4(f32x4 x) {
  bf16_4 w; w[0]=(__bf16)x[0]; w[1]=(__bf16)x[1]; w[2]=(__bf16)x[2]; w[3]=(__bf16)x[3];
  return w;
}

// ---------------- pre-pass: K pack + V^T fragment pack in one launch ----------------
// blocks [0, KPACK_BLOCKS): K -> bf16 [bh*n][152], one thread = one 16B chunk (19/row)
// blocks [KPACK_BLOCKS, +1024): V^T -> fragment-ordered [tile][g=ks*2+hi][d][8 bf16]
//   chunk (g,d) = { V[n0 + g*8 + j][d] : j=0..7 }  (one 16B store per chunk)
__global__ __launch_bounds__(256)
void pack_kv(const float* __restrict__ kmv, const float* __restrict__ ks_,
             const float* __restrict__ vmv, const float* __restrict__ vs,
             __bf16* __restrict__ kp, __bf16* __restrict__ vt) {
  __shared__ __align__(16) __bf16 sT[64 * TSTR];   // 19968 B (V branch only)
  const int t = threadIdx.x;
  const int b = blockIdx.x;
  if (b < KPACK_BLOCKS) {
    const unsigned g = b * 256u + t;               // < 65536*19
    const unsigned row = g / 19u, seg = g - row * 19u;
    bf16_8 o;
    if (seg < 16) {
      const f32x4* p = (const f32x4*)(kmv + (size_t)row * DMV + seg * 8);
      f32x4 a = p[0], bb = p[1];
#pragma unroll
      for (int j = 0; j < 8; ++j) o[j] = (__bf16)((j < 4) ? a[j] : bb[j - 4]);
    } else if (seg < 18) {
      const f32x4* p = (const f32x4*)(ks_ + (size_t)row * DS + (seg - 16) * 8);
      f32x4 a = p[0], bb = p[1];
#pragma unroll
      for (int j = 0; j < 8; ++j) o[j] = (__bf16)((j < 4) ? a[j] : bb[j - 4]);
    } else {
#pragma unroll
      for (int j = 0; j < 8; ++j) o[j] = (__bf16)0.0f;
    }
    *(bf16_8*)(kp + (size_t)row * KSTR + seg * 8) = o;
    return;
  }
  // ---- V^T pack: rows n of V -> LDS [n][d] (vector bf16_4 writes, verified R5) ----
  const int tile = b - KPACK_BLOCKS;               // bh*32 + nb
  const int n = t >> 2, c = t & 3;
  const float* mv = vmv + (size_t)(tile * 64 + n) * DMV;
  const float* sv = vs  + (size_t)(tile * 64 + n) * DS;
  __bf16* row = &sT[n * TSTR];
  if (c < 3) {
#pragma unroll
    for (int i = 0; i < 9; ++i)
      *(bf16_4*)&row[c * 36 + 4 * i] = cvt4(*(const f32x4*)(mv + c * 36 + 4 * i));
  } else {
#pragma unroll
    for (int i = 0; i < 5; ++i)
      *(bf16_4*)&row[108 + 4 * i] = cvt4(*(const f32x4*)(mv + 108 + 4 * i));
#pragma unroll
    for (int i = 0; i < 4; ++i)
      *(bf16_4*)&row[128 + 4 * i] = cvt4(*(const f32x4*)(sv + 4 * i));
  }
  __syncthreads();
  // ---- store side: chunk c = g*144 + d, gather 8 n's at fixed d, one 16B store ----
  bf16_8* vtt = (bf16_8*)vt + (size_t)tile * VT_CHUNKS;
#pragma unroll
  for (int s = 0; s < 5; ++s) {
    int cc = t + 256 * s;
    if (cc < VT_CHUNKS) {
      int g = cc / 144, d = cc - g * 144;
      bf16_8 o;
#pragma unroll
      for (int j = 0; j < 8; ++j) o[j] = sT[(g * 8 + j) * TSTR + d];
      vtt[cc] = o;
    }
  }
}

// ---------------- Q fragment load: IPF sign + scale, fp32 -> bf16 (k0 multiple of 8) --
__device__ __forceinline__ bf16_8 load_q_frag(const float* qmv_row, const float* qs_row, int k0) {
  bf16_8 f;
  if (k0 < DMV) {
    const f32x4* p = (const f32x4*)(qmv_row + k0);
    f32x4 a = p[0], b = p[1];
    // IPF = [1,1,-1,-1,-1,-1,-1,-1, 1,1,1,1,1,1,-1,-1]; k0&8 selects which half.
    int hi8 = k0 & 8;
#pragma unroll
    for (int j = 0; j < 8; ++j) {
      float v = (j < 4) ? a[j] : b[j - 4];
      bool pos = hi8 ? (j < 6) : (j < 2);
      f[j] = (__bf16)(v * (pos ? QSCALE : -QSCALE));
    }
  } else {
    const f32x4* p = (const f32x4*)(qs_row + (k0 - DMV));
    f32x4 a = p[0], b = p[1];
#pragma unroll
    for (int j = 0; j < 8; ++j) {
      float v = (j < 4) ? a[j] : b[j - 4];
      f[j] = (__bf16)(v * QSCALE);
    }
  }
  return f;
}

// ---------------- main flash kernel (512 threads, 8 waves x 32 Q-rows) ---------------
__global__ __launch_bounds__(512, 2)
void geo_attn_kernel(const float* __restrict__ q_mv, const float* __restrict__ q_s,
                     const __bf16* __restrict__ kp, const __bf16* __restrict__ vt,
                     float* __restrict__ out)
{
  __shared__ __align__(16) __bf16 sK[2][BN * KSTR];       // 2 x 19456 B = 38912 B

  const int tid  = threadIdx.x;
  const int w    = tid >> 6;        // wave 0..7
  const int lane = tid & 63;
  const int c32  = lane & 31;
  const int hi   = lane >> 5;
  // XCD-chunked swizzle: all 8 q-blocks of a bh on one XCD (xcd = flat % 8)
  const int flat = blockIdx.x;           // 0..255
  const int xcd  = flat & 7;
  const int jj   = flat >> 3;            // 0..31
  const int bh   = xcd * 4 + (jj & 3);
  const int qb   = jj >> 2;              // 0..7
  const int qbase = qb * BM;
  const size_t bh_n = (size_t)bh * N_;

  // ---- Q fragments in registers: B-operand layout, col m = c32, k = ks*16 + hi*8 + j
  bf16_8 qf[9];
  {
    const int mrow = qbase + w * 32 + c32;
    const float* qmv_row = q_mv + (bh_n + mrow) * DMV;
    const float* qs_row  = q_s  + (bh_n + mrow) * DS;
#pragma unroll
    for (int ks = 0; ks < 9; ++ks)
      qf[ks] = load_q_frag(qmv_row, qs_row, ks * 16 + hi * 8);
  }

  f32x16 of[5];
#pragma unroll
  for (int dt = 0; dt < 5; ++dt)
#pragma unroll
    for (int r = 0; r < 16; ++r) of[dt][r] = 0.0f;
  float m_i = -INFINITY, l_i = 0.0f;    // per Q-row stat, row m = c32 (both hi copies)

  const __bf16* kbase = kp + bh_n * KSTR;
  const bf16_8* vbase = (const bf16_8*)vt + (size_t)bh * NKIT * VT_CHUNKS;

  // ======== K staging: issue DMA for tile `it` into buffer `bu` ========
  auto stage = [&](int it, int bu) {
    const __bf16* kt = kbase + (size_t)(it * BN) * KSTR;
    __bf16* dK = &sK[bu][0];
#pragma unroll
    for (int s = 0; s < 2; ++s)
      GLOAD_LDS16(kt + (tid + 512 * s) * 8, dK + (tid + 512 * s) * 8);
    if (tid < KCHUNKS - 1024)   // 192: waves 0..2
      GLOAD_LDS16(kt + (tid + 1024) * 8, dK + (tid + 1024) * 8);
  };

  stage(0, 0);           // prologue
  __syncthreads();       // tile 0 resident

  for (int it = 0; it < NKIT; ++it) {
    const int cur = it & 1;

    // ---- V fragments for THIS tile: direct L2->VGPR, coalesced 16B/lane ----
    // vf[ks][dt] lane (c32,hi) = V^T[d=dt*32+c32][n=ks*16+hi*8 .. +8]
    // (dt=4, c32>=16 reads are past-tile garbage -> only feeds unused output cols)
    bf16_8 vf[4][5];
    {
      const bf16_8* vtile = vbase + (size_t)it * VT_CHUNKS + (hi * 144 + c32);
#pragma unroll
      for (int ks = 0; ks < 4; ++ks)
#pragma unroll
        for (int dt = 0; dt < 5; ++dt)
          vf[ks][dt] = vtile[ks * 288 + dt * 32];
    }

    if (it + 1 < NKIT) stage(it + 1, cur ^ 1);   // prefetch K: lands during compute

    // ======== S^T = K Q^T : sf[nt] rows n = nt*32 + (r&3)+8*(r>>2)+4*hi, cols m=c32 ==
    f32x16 sf[2];
#pragma unroll
    for (int nt = 0; nt < 2; ++nt)
#pragma unroll
      for (int r = 0; r < 16; ++r) sf[nt][r] = 0.0f;
    __builtin_amdgcn_s_setprio(1);
#pragma unroll
    for (int ks = 0; ks < 9; ++ks) {
      bf16_8 kb0 = *(const bf16_8*)&sK[cur][(c32)      * KSTR + ks * 16 + hi * 8];
      bf16_8 kb1 = *(const bf16_8*)&sK[cur][(32 + c32) * KSTR + ks * 16 + hi * 8];
      sf[0] = mfma32(kb0, qf[ks], sf[0]);
      sf[1] = mfma32(kb1, qf[ks], sf[1]);
    }
    __builtin_amdgcn_s_setprio(0);

    // ======== online softmax: row m = c32 fully lane-local (32 vals) + 1 shuffle ====
    float al = 1.0f, m_use;
    {
      float mx = sf[0][0];
#pragma unroll
      for (int r = 1; r < 16; ++r) mx = fmaxf(mx, sf[0][r]);
#pragma unroll
      for (int r = 0; r < 16; ++r) mx = fmaxf(mx, sf[1][r]);
      mx = fmaxf(mx, __shfl_xor(mx, 32));

      // T13 deferred rescale: keep old max while growth <= 8 (P bounded by 2^8)
      if (__all(mx <= m_i + 8.0f)) {
        m_use = m_i;
      } else {
        float mnew = fmaxf(m_i, mx);
        al = __builtin_amdgcn_exp2f(m_i - mnew);
        m_i = mnew; m_use = mnew;
        // redistribute al to O-row indexing (row m' = (r&3)+8*(r>>2)+4*hi)
#pragma unroll
        for (int r = 0; r < 16; ++r) {
          float a = __shfl(al, (r & 3) + 8 * (r >> 2) + 4 * hi);
#pragma unroll
          for (int dt = 0; dt < 5; ++dt) of[dt][r] *= a;
        }
      }
      float rs = 0.0f;
#pragma unroll
      for (int nt = 0; nt < 2; ++nt)
#pragma unroll
        for (int r = 0; r < 16; ++r) {
          float p = __builtin_amdgcn_exp2f(sf[nt][r] - m_use);
          sf[nt][r] = p;
          rs += p;
        }
      rs += __shfl_xor(rs, 32);
      l_i = l_i * al + rs;
    }

    // ======== O += P V, P assembled in-register (cvt_pk + permlane32_swap) ==========
#pragma unroll
    for (int ks = 0; ks < 4; ++ks) {
      const int nt = ks >> 1;
      const int Ra = 8 * (ks & 1);
      unsigned x0, x1, y0, y1;
      asm("v_cvt_pk_bf16_f32 %0, %1, %2" : "=v"(x0) : "v"(sf[nt][Ra + 0]), "v"(sf[nt][Ra + 1]));
      asm("v_cvt_pk_bf16_f32 %0, %1, %2" : "=v"(x1) : "v"(sf[nt][Ra + 2]), "v"(sf[nt][Ra + 3]));
      asm("v_cvt_pk_bf16_f32 %0, %1, %2" : "=v"(y0) : "v"(sf[nt][Ra + 4]), "v"(sf[nt][Ra + 5]));
      asm("v_cvt_pk_bf16_f32 %0, %1, %2" : "=v"(y1) : "v"(sf[nt][Ra + 6]), "v"(sf[nt][Ra + 7]));
      auto s0 = __builtin_amdgcn_permlane32_swap(x0, y0, false, false);
      auto s1 = __builtin_amdgcn_permlane32_swap(x1, y1, false, false);
      union { unsigned u[4]; bf16_8 v; } pu;
      pu.u[0] = s0[0]; pu.u[1] = s1[0]; pu.u[2] = s0[1]; pu.u[3] = s1[1];
      __builtin_amdgcn_s_setprio(1);
#pragma unroll
      for (int dt = 0; dt < 5; ++dt)
        of[dt] = mfma32(pu.v, vf[ks][dt], of[dt]);
      __builtin_amdgcn_s_setprio(0);
    }
    __syncthreads();  // all sK[cur] reads done + prefetch DMA drained before reuse
  }

  // ======== epilogue: O /= l (redistributed to O-rows), write fp32 ========
  float* out_mv = out;
  float* out_s  = out + (size_t)BH * N_ * DMV;
#pragma unroll
  for (int r = 0; r < 16; ++r) {
    const int ml  = (r & 3) + 8 * (r >> 2) + 4 * hi;
    const float linv = __builtin_amdgcn_rcpf(__shfl(l_i, ml));
    const int row = qbase + w * 32 + ml;
#pragma unroll
    for (int dt = 0; dt < 4; ++dt)
      out_mv[(bh_n + row) * DMV + dt * 32 + c32] = of[dt][r] * linv;
    if (c32 < DS)
      out_s[(bh_n + row) * DS + c32] = of[4][r] * linv;
  }
}

extern "C" void kernel_launch(void* const* d_in, const int* in_sizes, int n_in,
                              void* d_out, int out_size, void* d_ws, size_t ws_size,
                              hipStream_t stream) {
  (void)in_sizes; (void)n_in; (void)out_size; (void)ws_size;
  const float* q_mv = (const float*)d_in[0];
  const float* k_mv = (const float*)d_in[1];
  const float* v_mv = (const float*)d_in[2];
  const float* q_s  = (const float*)d_in[3];
  const float* k_s  = (const float*)d_in[4];
  const float* v_s  = (const float*)d_in[5];
  float* out = (float*)d_out;

  __bf16* kp = (__bf16*)d_ws;                              // 19,922,944 B
  __bf16* vt = (__bf16*)((char*)d_ws + KP_BYTES);          // 18,874,368 B (+slack)

  pack_kv<<<KPACK_BLOCKS + BH * NKIT, 256, 0, stream>>>(k_mv, k_s, v_mv, v_s, kp, vt);

  geo_attn_kernel<<<dim3(256), 512, 0, stream>>>(q_mv, q_s, kp, vt, out);
}

// Round 4
// 241.866 us; speedup vs baseline: 1.0309x; 1.0309x over previous
//
#include <hip/hip_runtime.h>
#include <cstdint>
#include <math.h>

// GeometricAttention: B=4,H=8,N=2048, D = 8*16 (mv, IPF signs on q) + 16 (s) = 144
// R7: V back in LDS (R6's L1-direct V regressed: L1 ~64B/cyc < LDS ~128B/cyc).
// T15 software pipeline: per iter compute QK(t+1) || softmax(t) || PV(t) with two
// score register sets (sfA/sfB), K double-buffered, V triple-buffered (108KB LDS).
// Softmax max/sum as depth-5 trees (were serial 32-chains). XCD swizzle kept.

#define BH    32
#define N_    2048
#define DMV   128
#define DS    16
#define D_    144
#define BM    256          // Q rows per block (8 waves x 32 rows)
#define BN    64           // KV rows per iteration
#define NKIT  (N_ / BN)    // 32
#define KSTR  152          // packed K row stride (bf16): 144 data + 8 pad
#define VSTR  72           // packed V^T row stride (bf16): 64 data + 8 pad
#define SVROWS 160         // sVT rows: 144 data + 16 zero pad (dt=4 tile)
#define KCHUNKS (BN * KSTR / 8)   // 1216 16B chunks
#define VCHUNKS (D_ * VSTR / 8)   // 1296 16B chunks
#define KP_BYTES ((size_t)BH * N_ * KSTR * 2)   // 19,922,944
#define QSCALE 0.12022458674074693f  // (1/12) * log2(e)
#define KPACK_BLOCKS (BH * N_ * 19 / 256)       // 4864
#define TSTR  156          // V-pack LDS transpose stride

typedef __bf16 bf16_8 __attribute__((ext_vector_type(8)));
typedef __bf16 bf16_4 __attribute__((ext_vector_type(4)));
typedef __bf16 bf16_2 __attribute__((ext_vector_type(2)));
typedef float  f32x4  __attribute__((ext_vector_type(4)));
typedef float  f32x16 __attribute__((ext_vector_type(16)));

#define GLOAD_LDS16(g, l)                                                     \
  __builtin_amdgcn_global_load_lds(                                           \
      (const __attribute__((address_space(1))) void*)(g),                     \
      (__attribute__((address_space(3))) void*)(l), 16, 0, 0)

__device__ __forceinline__ f32x16 mfma32(bf16_8 a, bf16_8 b, f32x16 c) {
  return __builtin_amdgcn_mfma_f32_32x32x16_bf16(a, b, c, 0, 0, 0);
}

__device__ __forceinline__ bf16_4 cvt4(f32x4 x) {
  bf16_4 w; w[0]=(__bf16)x[0]; w[1]=(__bf16)x[1]; w[2]=(__bf16)x[2]; w[3]=(__bf16)x[3];
  return w;
}

// ---------------- pre-pass: K pack + V^T pack in one launch (R5-verified) -----------
__global__ __launch_bounds__(256)
void pack_kv(const float* __restrict__ kmv, const float* __restrict__ ks_,
             const float* __restrict__ vmv, const float* __restrict__ vs,
             __bf16* __restrict__ kp, __bf16* __restrict__ vt) {
  __shared__ __align__(16) __bf16 sT[64 * TSTR];   // 19968 B (V branch only)
  const int t = threadIdx.x;
  const int b = blockIdx.x;
  if (b < KPACK_BLOCKS) {
    const unsigned g = b * 256u + t;               // < 65536*19
    const unsigned row = g / 19u, seg = g - row * 19u;
    bf16_8 o;
    if (seg < 16) {
      const f32x4* p = (const f32x4*)(kmv + (size_t)row * DMV + seg * 8);
      f32x4 a = p[0], bb = p[1];
#pragma unroll
      for (int j = 0; j < 8; ++j) o[j] = (__bf16)((j < 4) ? a[j] : bb[j - 4]);
    } else if (seg < 18) {
      const f32x4* p = (const f32x4*)(ks_ + (size_t)row * DS + (seg - 16) * 8);
      f32x4 a = p[0], bb = p[1];
#pragma unroll
      for (int j = 0; j < 8; ++j) o[j] = (__bf16)((j < 4) ? a[j] : bb[j - 4]);
    } else {
#pragma unroll
      for (int j = 0; j < 8; ++j) o[j] = (__bf16)0.0f;
    }
    *(bf16_8*)(kp + (size_t)row * KSTR + seg * 8) = o;
    return;
  }
  // ---- V^T pack ----
  const int tile = b - KPACK_BLOCKS;               // bh*32 + nb
  const int n = t >> 2, c = t & 3;
  const float* mv = vmv + (size_t)(tile * 64 + n) * DMV;
  const float* sv = vs  + (size_t)(tile * 64 + n) * DS;
  __bf16* row = &sT[n * TSTR];
  if (c < 3) {
#pragma unroll
    for (int i = 0; i < 9; ++i)
      *(bf16_4*)&row[c * 36 + 4 * i] = cvt4(*(const f32x4*)(mv + c * 36 + 4 * i));
  } else {
#pragma unroll
    for (int i = 0; i < 5; ++i)
      *(bf16_4*)&row[108 + 4 * i] = cvt4(*(const f32x4*)(mv + 108 + 4 * i));
#pragma unroll
    for (int i = 0; i < 4; ++i)
      *(bf16_4*)&row[128 + 4 * i] = cvt4(*(const f32x4*)(sv + 4 * i));
  }
  __syncthreads();
  __bf16* vtt = vt + (size_t)tile * (D_ * VSTR);
#pragma unroll
  for (int k = 0; k < 18; ++k) {
    int idx = t + 256 * k;                // 4608 = 144 d x 32 j-pairs
    int d = idx >> 5, j = idx & 31;
    bf16_2 p; p[0] = sT[(2 * j) * TSTR + d]; p[1] = sT[(2 * j + 1) * TSTR + d];
    *(bf16_2*)&vtt[d * VSTR + 2 * j] = p; // 128B contiguous per 32 lanes
  }
}

// ---------------- Q fragment load: IPF sign + scale, fp32 -> bf16 (k0 multiple of 8) --
__device__ __forceinline__ bf16_8 load_q_frag(const float* qmv_row, const float* qs_row, int k0) {
  bf16_8 f;
  if (k0 < DMV) {
    const f32x4* p = (const f32x4*)(qmv_row + k0);
    f32x4 a = p[0], b = p[1];
    // IPF = [1,1,-1,-1,-1,-1,-1,-1, 1,1,1,1,1,1,-1,-1]; k0&8 selects which half.
    int hi8 = k0 & 8;
#pragma unroll
    for (int j = 0; j < 8; ++j) {
      float v = (j < 4) ? a[j] : b[j - 4];
      bool pos = hi8 ? (j < 6) : (j < 2);
      f[j] = (__bf16)(v * (pos ? QSCALE : -QSCALE));
    }
  } else {
    const f32x4* p = (const f32x4*)(qs_row + (k0 - DMV));
    f32x4 a = p[0], b = p[1];
#pragma unroll
    for (int j = 0; j < 8; ++j) {
      float v = (j < 4) ? a[j] : b[j - 4];
      f[j] = (__bf16)(v * QSCALE);
    }
  }
  return f;
}

// ---------------- main flash kernel (512 threads, 8 waves x 32 Q-rows) ---------------
__global__ __launch_bounds__(512, 2)
void geo_attn_kernel(const float* __restrict__ q_mv, const float* __restrict__ q_s,
                     const __bf16* __restrict__ kp, const __bf16* __restrict__ vt,
                     float* __restrict__ out)
{
  __shared__ __align__(16) __bf16 sK[2][BN * KSTR];       // 2 x 19456 = 38912 B
  __shared__ __align__(16) __bf16 sVT[3][SVROWS * VSTR];  // 3 x 23040 = 69120 B

  const int tid  = threadIdx.x;
  const int lane = tid & 63;
  const int w    = tid >> 6;
  const int c32  = lane & 31;
  const int hi   = lane >> 5;
  // XCD-chunked swizzle: all 8 q-blocks of a bh on one XCD (xcd = flat % 8)
  const int flat = blockIdx.x;           // 0..255
  const int xcd  = flat & 7;
  const int jj   = flat >> 3;            // 0..31
  const int bh   = xcd * 4 + (jj & 3);
  const int qb   = jj >> 2;              // 0..7
  const int qbase = qb * BM;
  const size_t bh_n = (size_t)bh * N_;

  // zero the d-pad rows 144..159 of all 3 sVT buffers once (staging never writes them)
  if (tid < 432) {
    int bb = tid / 144, cc = tid - bb * 144;
    f32x4 z = {0.f, 0.f, 0.f, 0.f};
    *(f32x4*)((char*)&sVT[bb][D_ * VSTR] + cc * 16) = z;
  }

  // ---- Q fragments in registers: B-operand layout, col m = c32, k = ks*16 + hi*8 + j
  bf16_8 qf[9];
  {
    const int mrow = qbase + w * 32 + c32;
    const float* qmv_row = q_mv + (bh_n + mrow) * DMV;
    const float* qs_row  = q_s  + (bh_n + mrow) * DS;
#pragma unroll
    for (int ks = 0; ks < 9; ++ks)
      qf[ks] = load_q_frag(qmv_row, qs_row, ks * 16 + hi * 8);
  }

  f32x16 of[5];
#pragma unroll
  for (int dt = 0; dt < 5; ++dt)
#pragma unroll
    for (int r = 0; r < 16; ++r) of[dt][r] = 0.0f;
  float m_i = -INFINITY, l_i = 0.0f;    // per Q-row stat, row m = c32 (both hi copies)

  const __bf16* kbase = kp + bh_n * KSTR;
  const __bf16* vbase = vt + (size_t)bh * NKIT * (D_ * VSTR);

  auto stageK = [&](int it, int bu) {
    const __bf16* kt = kbase + (size_t)(it * BN) * KSTR;
    __bf16* dK = &sK[bu][0];
    GLOAD_LDS16(kt + tid * 8, dK + tid * 8);
    GLOAD_LDS16(kt + (tid + 512) * 8, dK + (tid + 512) * 8);
    if (tid < KCHUNKS - 1024)   // 192
      GLOAD_LDS16(kt + (tid + 1024) * 8, dK + (tid + 1024) * 8);
  };
  auto stageV = [&](int it, int bu) {
    const __bf16* vtt = vbase + (size_t)it * (D_ * VSTR);
    __bf16* dV = &sVT[bu][0];
    GLOAD_LDS16(vtt + tid * 8, dV + tid * 8);
    GLOAD_LDS16(vtt + (tid + 512) * 8, dV + (tid + 512) * 8);
    if (tid < VCHUNKS - 1024)   // 272
      GLOAD_LDS16(vtt + (tid + 1024) * 8, dV + (tid + 1024) * 8);
  };

  // QK(tile) from K buffer kb -> sn (S^T: rows n = nt*32+(r&3)+8*(r>>2)+4*hi, col m=c32)
  auto qk = [&](int kb, f32x16 (&sn)[2]) {
#pragma unroll
    for (int nt = 0; nt < 2; ++nt)
#pragma unroll
      for (int r = 0; r < 16; ++r) sn[nt][r] = 0.0f;
    __builtin_amdgcn_s_setprio(1);
#pragma unroll
    for (int ks = 0; ks < 9; ++ks) {
      bf16_8 kb0 = *(const bf16_8*)&sK[kb][(c32)      * KSTR + ks * 16 + hi * 8];
      bf16_8 kb1 = *(const bf16_8*)&sK[kb][(32 + c32) * KSTR + ks * 16 + hi * 8];
      sn[0] = mfma32(kb0, qf[ks], sn[0]);
      sn[1] = mfma32(kb1, qf[ks], sn[1]);
    }
    __builtin_amdgcn_s_setprio(0);
  };

  // ---- per-iteration pipelined body: QK(t+1) || softmax(t) || PV(t) ----
  auto body = [&](int t, f32x16 (&sfc)[2], f32x16 (&sfn)[2]) {
    __syncthreads();     // DMA(t+1) drained; all waves' tile(t-1) reads done
    if (t + 2 < NKIT) {  // stage tile t+2 (K into kbuf t&1, V into vbuf (t+2)%3)
      stageK(t + 2, t & 1);
      stageV(t + 2, (t + 2) % 3);
    }
    if (t + 1 < NKIT)    // QK for NEXT tile: independent of softmax(t) below
      qk((t + 1) & 1, sfn);

    // ======== softmax(t): depth-5 trees, deferred rescale (T13, THR=8) ========
    float al = 1.0f, m_use;
    {
      float a[8];
#pragma unroll
      for (int r = 0; r < 8; ++r)
        a[r] = fmaxf(fmaxf(sfc[0][r], sfc[0][r + 8]), fmaxf(sfc[1][r], sfc[1][r + 8]));
      float mx = fmaxf(fmaxf(fmaxf(a[0], a[1]), fmaxf(a[2], a[3])),
                       fmaxf(fmaxf(a[4], a[5]), fmaxf(a[6], a[7])));
      mx = fmaxf(mx, __shfl_xor(mx, 32));

      if (__all(mx <= m_i + 8.0f)) {
        m_use = m_i;
      } else {
        float mnew = fmaxf(m_i, mx);
        al = __builtin_amdgcn_exp2f(m_i - mnew);
        m_i = mnew; m_use = mnew;
#pragma unroll
        for (int r = 0; r < 16; ++r) {
          float aa = __shfl(al, (r & 3) + 8 * (r >> 2) + 4 * hi);
#pragma unroll
          for (int dt = 0; dt < 5; ++dt) of[dt][r] *= aa;
        }
      }
#pragma unroll
      for (int nt = 0; nt < 2; ++nt)
#pragma unroll
        for (int r = 0; r < 16; ++r)
          sfc[nt][r] = __builtin_amdgcn_exp2f(sfc[nt][r] - m_use);
      float s8[8];
#pragma unroll
      for (int r = 0; r < 8; ++r)
        s8[r] = (sfc[0][r] + sfc[0][r + 8]) + (sfc[1][r] + sfc[1][r + 8]);
      float rs = ((s8[0] + s8[1]) + (s8[2] + s8[3])) + ((s8[4] + s8[5]) + (s8[6] + s8[7]));
      rs += __shfl_xor(rs, 32);
      l_i = l_i * al + rs;
    }

    // ======== PV(t): P in-register (cvt_pk + permlane32_swap), V from vbuf t%3 ====
    const __bf16* sV = &sVT[t % 3][0];
#pragma unroll
    for (int ks = 0; ks < 4; ++ks) {
      const int nt = ks >> 1;
      const int Ra = 8 * (ks & 1);
      unsigned x0, x1, y0, y1;
      asm("v_cvt_pk_bf16_f32 %0, %1, %2" : "=v"(x0) : "v"(sfc[nt][Ra + 0]), "v"(sfc[nt][Ra + 1]));
      asm("v_cvt_pk_bf16_f32 %0, %1, %2" : "=v"(x1) : "v"(sfc[nt][Ra + 2]), "v"(sfc[nt][Ra + 3]));
      asm("v_cvt_pk_bf16_f32 %0, %1, %2" : "=v"(y0) : "v"(sfc[nt][Ra + 4]), "v"(sfc[nt][Ra + 5]));
      asm("v_cvt_pk_bf16_f32 %0, %1, %2" : "=v"(y1) : "v"(sfc[nt][Ra + 6]), "v"(sfc[nt][Ra + 7]));
      auto s0 = __builtin_amdgcn_permlane32_swap(x0, y0, false, false);
      auto s1 = __builtin_amdgcn_permlane32_swap(x1, y1, false, false);
      union { unsigned u[4]; bf16_8 v; } pu;
      pu.u[0] = s0[0]; pu.u[1] = s1[0]; pu.u[2] = s0[1]; pu.u[3] = s1[1];
      __builtin_amdgcn_s_setprio(1);
#pragma unroll
      for (int dt = 0; dt < 5; ++dt) {
        bf16_8 vb = *(const bf16_8*)&sV[(dt * 32 + c32) * VSTR + ks * 16 + hi * 8];
        of[dt] = mfma32(pu.v, vb, of[dt]);
      }
      __builtin_amdgcn_s_setprio(0);
    }
  };

  // ---- prologue: stage 0, compute QK(0), stage 1 ----
  f32x16 sfA[2], sfB[2];
  stageK(0, 0); stageV(0, 0);
  __syncthreads();
  qk(0, sfA);
  stageK(1, 1); stageV(1, 1);

  for (int t2 = 0; t2 < NKIT; t2 += 2) {
    body(t2,     sfA, sfB);
    body(t2 + 1, sfB, sfA);
  }

  // ======== epilogue: O /= l (redistributed to O-rows), write fp32 ========
  float* out_mv = out;
  float* out_s  = out + (size_t)BH * N_ * DMV;
#pragma unroll
  for (int r = 0; r < 16; ++r) {
    const int ml  = (r & 3) + 8 * (r >> 2) + 4 * hi;
    const float linv = __builtin_amdgcn_rcpf(__shfl(l_i, ml));
    const int row = qbase + w * 32 + ml;
#pragma unroll
    for (int dt = 0; dt < 4; ++dt)
      out_mv[(bh_n + row) * DMV + dt * 32 + c32] = of[dt][r] * linv;
    if (c32 < DS)
      out_s[(bh_n + row) * DS + c32] = of[4][r] * linv;
  }
}

extern "C" void kernel_launch(void* const* d_in, const int* in_sizes, int n_in,
                              void* d_out, int out_size, void* d_ws, size_t ws_size,
                              hipStream_t stream) {
  (void)in_sizes; (void)n_in; (void)out_size; (void)ws_size;
  const float* q_mv = (const float*)d_in[0];
  const float* k_mv = (const float*)d_in[1];
  const float* v_mv = (const float*)d_in[2];
  const float* q_s  = (const float*)d_in[3];
  const float* k_s  = (const float*)d_in[4];
  const float* v_s  = (const float*)d_in[5];
  float* out = (float*)d_out;

  __bf16* kp = (__bf16*)d_ws;                              // 19,922,944 B
  __bf16* vt = (__bf16*)((char*)d_ws + KP_BYTES);          // 21,233,664 B

  pack_kv<<<KPACK_BLOCKS + BH * NKIT, 256, 0, stream>>>(k_mv, k_s, v_mv, v_s, kp, vt);

  geo_attn_kernel<<<dim3(256), 512, 0, stream>>>(q_mv, q_s, kp, vt, out);
}

// Round 5
// 241.658 us; speedup vs baseline: 1.0318x; 1.0009x over previous
//
#include <hip/hip_runtime.h>
#include <cstdint>
#include <math.h>

// GeometricAttention: B=4,H=8,N=2048, D = 8*16 (mv, IPF signs on q) + 16 (s) = 144
// R8: inter-wave ROLE SKEW. 8 waves, role=(w>>2)&1 so each SIMD hosts one wave of
// each role. Even waves: [QK(t); SM(t); PV(t)]. Odd waves: [SM(t-1); PV(t-1); QK(t)]
// (online softmax is tile-order invariant). At any instant each SIMD mixes an
// MFMA/LDS-heavy wave with a VALU/trans-heavy wave -> pipes overlap instead of
// phase-serial lockstep (R4/R5/R7 all ~106us = sum of pipe times, not max).
// K dbuf + V tripple-buf (101KB LDS), one barrier per body. Packs split (best residual).

#define BH    32
#define N_    2048
#define DMV   128
#define DS    16
#define D_    144
#define BM    256          // Q rows per block (8 waves x 32 rows)
#define BN    64           // KV rows per iteration
#define NKIT  (N_ / BN)    // 32
#define KSTR  152          // packed K row stride (bf16): 144 data + 8 pad
#define VSTR  72           // packed V^T row stride (bf16): 64 data + 8 pad
#define KCHUNKS (BN * KSTR / 8)   // 1216 16B chunks
#define VCHUNKS (D_ * VSTR / 8)   // 1296 16B chunks
#define KP_BYTES ((size_t)BH * N_ * KSTR * 2)   // 19,922,944
#define QSCALE 0.12022458674074693f  // (1/12) * log2(e)
#define TSTR  156          // V-pack LDS transpose stride

typedef __bf16 bf16_8 __attribute__((ext_vector_type(8)));
typedef __bf16 bf16_4 __attribute__((ext_vector_type(4)));
typedef __bf16 bf16_2 __attribute__((ext_vector_type(2)));
typedef float  f32x4  __attribute__((ext_vector_type(4)));
typedef float  f32x16 __attribute__((ext_vector_type(16)));

#define GLOAD_LDS16(g, l)                                                     \
  __builtin_amdgcn_global_load_lds(                                           \
      (const __attribute__((address_space(1))) void*)(g),                     \
      (__attribute__((address_space(3))) void*)(l), 16, 0, 0)

__device__ __forceinline__ f32x16 mfma32(bf16_8 a, bf16_8 b, f32x16 c) {
  return __builtin_amdgcn_mfma_f32_32x32x16_bf16(a, b, c, 0, 0, 0);
}

__device__ __forceinline__ bf16_4 cvt4(f32x4 x) {
  bf16_4 w; w[0]=(__bf16)x[0]; w[1]=(__bf16)x[1]; w[2]=(__bf16)x[2]; w[3]=(__bf16)x[3];
  return w;
}

// ---------------- pre-pass 1: K -> bf16 packed [bh*n][152] --------------------------
__global__ __launch_bounds__(256)
void pack_k(const float* __restrict__ kmv, const float* __restrict__ ks_,
            __bf16* __restrict__ kp) {
  const unsigned g = blockIdx.x * 256u + threadIdx.x;   // < 65536*19
  const unsigned row = g / 19u, seg = g - row * 19u;
  bf16_8 o;
  if (seg < 16) {
    const f32x4* p = (const f32x4*)(kmv + (size_t)row * DMV + seg * 8);
    f32x4 a = p[0], bb = p[1];
#pragma unroll
    for (int j = 0; j < 8; ++j) o[j] = (__bf16)((j < 4) ? a[j] : bb[j - 4]);
  } else if (seg < 18) {
    const f32x4* p = (const f32x4*)(ks_ + (size_t)row * DS + (seg - 16) * 8);
    f32x4 a = p[0], bb = p[1];
#pragma unroll
    for (int j = 0; j < 8; ++j) o[j] = (__bf16)((j < 4) ? a[j] : bb[j - 4]);
  } else {
#pragma unroll
    for (int j = 0; j < 8; ++j) o[j] = (__bf16)0.0f;
  }
  *(bf16_8*)(kp + (size_t)row * KSTR + seg * 8) = o;
}

// ---------------- pre-pass 2: V^T -> bf16 tile-blocked [bh*32 tiles][144][72] -------
__global__ __launch_bounds__(256)
void pack_vt(const float* __restrict__ vmv, const float* __restrict__ vs,
             __bf16* __restrict__ vt) {
  __shared__ __align__(16) __bf16 sT[64 * TSTR];
  const int tile = blockIdx.x;            // bh*32 + nb
  const int t = threadIdx.x;
  const int n = t >> 2, c = t & 3;
  const float* mv = vmv + (size_t)(tile * 64 + n) * DMV;
  const float* sv = vs  + (size_t)(tile * 64 + n) * DS;
  __bf16* row = &sT[n * TSTR];
  if (c < 3) {
#pragma unroll
    for (int i = 0; i < 9; ++i)
      *(bf16_4*)&row[c * 36 + 4 * i] = cvt4(*(const f32x4*)(mv + c * 36 + 4 * i));
  } else {
#pragma unroll
    for (int i = 0; i < 5; ++i)
      *(bf16_4*)&row[108 + 4 * i] = cvt4(*(const f32x4*)(mv + 108 + 4 * i));
#pragma unroll
    for (int i = 0; i < 4; ++i)
      *(bf16_4*)&row[128 + 4 * i] = cvt4(*(const f32x4*)(sv + 4 * i));
  }
  __syncthreads();
  __bf16* vtt = vt + (size_t)tile * (D_ * VSTR);
#pragma unroll
  for (int k = 0; k < 18; ++k) {
    int idx = t + 256 * k;                // 4608 = 144 d x 32 j-pairs
    int d = idx >> 5, j = idx & 31;
    bf16_2 p; p[0] = sT[(2 * j) * TSTR + d]; p[1] = sT[(2 * j + 1) * TSTR + d];
    *(bf16_2*)&vtt[d * VSTR + 2 * j] = p; // 128B contiguous per 32 lanes
  }
}

// ---------------- Q fragment load: IPF sign + scale, fp32 -> bf16 (k0 multiple of 8) --
__device__ __forceinline__ bf16_8 load_q_frag(const float* qmv_row, const float* qs_row, int k0) {
  bf16_8 f;
  if (k0 < DMV) {
    const f32x4* p = (const f32x4*)(qmv_row + k0);
    f32x4 a = p[0], b = p[1];
    // IPF = [1,1,-1,-1,-1,-1,-1,-1, 1,1,1,1,1,1,-1,-1]; k0&8 selects which half.
    int hi8 = k0 & 8;
#pragma unroll
    for (int j = 0; j < 8; ++j) {
      float v = (j < 4) ? a[j] : b[j - 4];
      bool pos = hi8 ? (j < 6) : (j < 2);
      f[j] = (__bf16)(v * (pos ? QSCALE : -QSCALE));
    }
  } else {
    const f32x4* p = (const f32x4*)(qs_row + (k0 - DMV));
    f32x4 a = p[0], b = p[1];
#pragma unroll
    for (int j = 0; j < 8; ++j) {
      float v = (j < 4) ? a[j] : b[j - 4];
      f[j] = (__bf16)(v * QSCALE);
    }
  }
  return f;
}

// ---------------- main flash kernel (512 threads, 8 waves x 32 Q-rows) ---------------
__global__ __launch_bounds__(512, 2)
void geo_attn_kernel(const float* __restrict__ q_mv, const float* __restrict__ q_s,
                     const __bf16* __restrict__ kp, const __bf16* __restrict__ vt,
                     float* __restrict__ out)
{
  // sVT first: PV dt=4 reads up to 2.3KB past a V buffer; for the last buffer those
  // land in sK (defined garbage) and feed only discarded output cols (c32>=16).
  __shared__ __align__(16) __bf16 sVT[3][D_ * VSTR];  // 3 x 20736 = 62208 B
  __shared__ __align__(16) __bf16 sK[2][BN * KSTR];   // 2 x 19456 = 38912 B (101120)

  const int tid  = threadIdx.x;
  const int lane = tid & 63;
  const int w    = tid >> 6;
  const int role = (w >> 2) & 1;    // SIMD s hosts wave s (role 0) + wave s+4 (role 1)
  const int c32  = lane & 31;
  const int hi   = lane >> 5;
  // XCD-chunked swizzle: all 8 q-blocks of a bh on one XCD (xcd = flat % 8)
  const int flat = blockIdx.x;           // 0..255
  const int xcd  = flat & 7;
  const int jj   = flat >> 3;            // 0..31
  const int bh   = xcd * 4 + (jj & 3);
  const int qb   = jj >> 2;              // 0..7
  const int qbase = qb * BM;
  const size_t bh_n = (size_t)bh * N_;

  // ---- Q fragments in registers: B-operand layout, col m = c32, k = ks*16 + hi*8 + j
  bf16_8 qf[9];
  {
    const int mrow = qbase + w * 32 + c32;
    const float* qmv_row = q_mv + (bh_n + mrow) * DMV;
    const float* qs_row  = q_s  + (bh_n + mrow) * DS;
#pragma unroll
    for (int ks = 0; ks < 9; ++ks)
      qf[ks] = load_q_frag(qmv_row, qs_row, ks * 16 + hi * 8);
  }

  f32x16 of[5];
#pragma unroll
  for (int dt = 0; dt < 5; ++dt)
#pragma unroll
    for (int r = 0; r < 16; ++r) of[dt][r] = 0.0f;
  float m_i = -INFINITY, l_i = 0.0f;    // per Q-row stat, row m = c32 (both hi copies)

  const __bf16* kbase = kp + bh_n * KSTR;
  const __bf16* vbase = vt + (size_t)bh * NKIT * (D_ * VSTR);

  auto stage = [&](int it) {     // K(it)->kb[it&1], V(it)->vb[it%3]
    const __bf16* kt = kbase + (size_t)(it * BN) * KSTR;
    __bf16* dK = &sK[it & 1][0];
    GLOAD_LDS16(kt + tid * 8, dK + tid * 8);
    GLOAD_LDS16(kt + (tid + 512) * 8, dK + (tid + 512) * 8);
    if (tid < KCHUNKS - 1024)   // 192
      GLOAD_LDS16(kt + (tid + 1024) * 8, dK + (tid + 1024) * 8);
    const __bf16* vtt = vbase + (size_t)it * (D_ * VSTR);
    __bf16* dV = &sVT[it % 3][0];
    GLOAD_LDS16(vtt + tid * 8, dV + tid * 8);
    GLOAD_LDS16(vtt + (tid + 512) * 8, dV + (tid + 512) * 8);
    if (tid < VCHUNKS - 1024)   // 272
      GLOAD_LDS16(vtt + (tid + 1024) * 8, dV + (tid + 1024) * 8);
  };

  // QK(t): S^T rows n = nt*32 + (r&3)+8*(r>>2)+4*hi, cols m = c32
  f32x16 sf[2];
  auto qk = [&](int t) {
    const __bf16* sKt = &sK[t & 1][0];
#pragma unroll
    for (int nt = 0; nt < 2; ++nt)
#pragma unroll
      for (int r = 0; r < 16; ++r) sf[nt][r] = 0.0f;
    __builtin_amdgcn_s_setprio(1);
#pragma unroll
    for (int ks = 0; ks < 9; ++ks) {
      bf16_8 kb0 = *(const bf16_8*)&sKt[(c32)      * KSTR + ks * 16 + hi * 8];
      bf16_8 kb1 = *(const bf16_8*)&sKt[(32 + c32) * KSTR + ks * 16 + hi * 8];
      sf[0] = mfma32(kb0, qf[ks], sf[0]);
      sf[1] = mfma32(kb1, qf[ks], sf[1]);
    }
    __builtin_amdgcn_s_setprio(0);
  };

  // softmax on sf: depth-5 trees, deferred rescale (T13, THR=8)
  auto sm = [&]() {
    float al = 1.0f, m_use;
    float a[8];
#pragma unroll
    for (int r = 0; r < 8; ++r)
      a[r] = fmaxf(fmaxf(sf[0][r], sf[0][r + 8]), fmaxf(sf[1][r], sf[1][r + 8]));
    float mx = fmaxf(fmaxf(fmaxf(a[0], a[1]), fmaxf(a[2], a[3])),
                     fmaxf(fmaxf(a[4], a[5]), fmaxf(a[6], a[7])));
    mx = fmaxf(mx, __shfl_xor(mx, 32));

    if (__all(mx <= m_i + 8.0f)) {
      m_use = m_i;
    } else {
      float mnew = fmaxf(m_i, mx);
      al = __builtin_amdgcn_exp2f(m_i - mnew);
      m_i = mnew; m_use = mnew;
#pragma unroll
      for (int r = 0; r < 16; ++r) {
        float aa = __shfl(al, (r & 3) + 8 * (r >> 2) + 4 * hi);
#pragma unroll
        for (int dt = 0; dt < 5; ++dt) of[dt][r] *= aa;
      }
    }
#pragma unroll
    for (int nt = 0; nt < 2; ++nt)
#pragma unroll
      for (int r = 0; r < 16; ++r)
        sf[nt][r] = __builtin_amdgcn_exp2f(sf[nt][r] - m_use);
    float s8[8];
#pragma unroll
    for (int r = 0; r < 8; ++r)
      s8[r] = (sf[0][r] + sf[0][r + 8]) + (sf[1][r] + sf[1][r + 8]);
    float rs = ((s8[0] + s8[1]) + (s8[2] + s8[3])) + ((s8[4] + s8[5]) + (s8[6] + s8[7]));
    rs += __shfl_xor(rs, 32);
    l_i = l_i * al + rs;
  };

  // PV(t): P in-register (cvt_pk + permlane32_swap), V from vb[t%3]
  auto pv = [&](int t) {
    const __bf16* sV = &sVT[t % 3][0];
#pragma unroll
    for (int ks = 0; ks < 4; ++ks) {
      const int nt = ks >> 1;
      const int Ra = 8 * (ks & 1);
      unsigned x0, x1, y0, y1;
      asm("v_cvt_pk_bf16_f32 %0, %1, %2" : "=v"(x0) : "v"(sf[nt][Ra + 0]), "v"(sf[nt][Ra + 1]));
      asm("v_cvt_pk_bf16_f32 %0, %1, %2" : "=v"(x1) : "v"(sf[nt][Ra + 2]), "v"(sf[nt][Ra + 3]));
      asm("v_cvt_pk_bf16_f32 %0, %1, %2" : "=v"(y0) : "v"(sf[nt][Ra + 4]), "v"(sf[nt][Ra + 5]));
      asm("v_cvt_pk_bf16_f32 %0, %1, %2" : "=v"(y1) : "v"(sf[nt][Ra + 6]), "v"(sf[nt][Ra + 7]));
      auto s0 = __builtin_amdgcn_permlane32_swap(x0, y0, false, false);
      auto s1 = __builtin_amdgcn_permlane32_swap(x1, y1, false, false);
      union { unsigned u[4]; bf16_8 v; } pu;
      pu.u[0] = s0[0]; pu.u[1] = s1[0]; pu.u[2] = s0[1]; pu.u[3] = s1[1];
      __builtin_amdgcn_s_setprio(1);
#pragma unroll
      for (int dt = 0; dt < 5; ++dt) {
        bf16_8 vb = *(const bf16_8*)&sV[(dt * 32 + c32) * VSTR + ks * 16 + hi * 8];
        of[dt] = mfma32(pu.v, vb, of[dt]);
      }
      __builtin_amdgcn_s_setprio(0);
    }
  };

  // ---- prologue: tile 0 resident ----
  stage(0);
  __syncthreads();

  for (int t = 0; t < NKIT; ++t) {
    if (t + 1 < NKIT) stage(t + 1);
    if (role == 0) {
      qk(t); sm(); pv(t);              // even waves: current tile
    } else {
      if (t > 0) { sm(); pv(t - 1); }  // odd waves: finish previous tile, then QK(t)
      qk(t);
    }
    __syncthreads();   // drains stage(t+1) DMA; all tile(t-1..t) reads complete
  }
  if (role == 1) { sm(); pv(NKIT - 1); }   // odd-role epilogue

  // ======== epilogue: O /= l (redistributed to O-rows), write fp32 ========
  float* out_mv = out;
  float* out_s  = out + (size_t)BH * N_ * DMV;
#pragma unroll
  for (int r = 0; r < 16; ++r) {
    const int ml  = (r & 3) + 8 * (r >> 2) + 4 * hi;
    const float linv = __builtin_amdgcn_rcpf(__shfl(l_i, ml));
    const int row = qbase + w * 32 + ml;
#pragma unroll
    for (int dt = 0; dt < 4; ++dt)
      out_mv[(bh_n + row) * DMV + dt * 32 + c32] = of[dt][r] * linv;
    if (c32 < DS)
      out_s[(bh_n + row) * DS + c32] = of[4][r] * linv;
  }
}

extern "C" void kernel_launch(void* const* d_in, const int* in_sizes, int n_in,
                              void* d_out, int out_size, void* d_ws, size_t ws_size,
                              hipStream_t stream) {
  (void)in_sizes; (void)n_in; (void)out_size; (void)ws_size;
  const float* q_mv = (const float*)d_in[0];
  const float* k_mv = (const float*)d_in[1];
  const float* v_mv = (const float*)d_in[2];
  const float* q_s  = (const float*)d_in[3];
  const float* k_s  = (const float*)d_in[4];
  const float* v_s  = (const float*)d_in[5];
  float* out = (float*)d_out;

  __bf16* kp = (__bf16*)d_ws;                              // 19,922,944 B
  __bf16* vt = (__bf16*)((char*)d_ws + KP_BYTES);          // 21,233,664 B

  pack_k<<<(BH * N_ * 19) / 256, 256, 0, stream>>>(k_mv, k_s, kp);
  pack_vt<<<BH * NKIT, 256, 0, stream>>>(v_mv, v_s, vt);

  geo_attn_kernel<<<dim3(256), 512, 0, stream>>>(q_mv, q_s, kp, vt, out);
}